// Round 13
// baseline (192.629 us; speedup 1.0000x reference)
//
#include <hip/hip_runtime.h>
#include <math.h>

#define N 8192
#define FIN 128
#define FOUT 64
#define ALPHA 0.2f
#define JS 16
#define JLEN (N / JS)          // 512
#define NT (JLEN / 32)         // 16 j-tiles per block

typedef __attribute__((ext_vector_type(8))) short bf16x8;
typedef __attribute__((ext_vector_type(8))) unsigned short ushort8;
typedef __attribute__((ext_vector_type(4))) float f32x4;
typedef __attribute__((ext_vector_type(4))) int i32x4;

__device__ __forceinline__ unsigned f2bf(float f) {
    unsigned int u = __float_as_uint(f);
    u += 0x7fff + ((u >> 16) & 1);          // round-to-nearest-even
    return u >> 16;
}
__device__ __forceinline__ float elu(float v) { return v > 0.f ? v : expm1f(v); }
__device__ __forceinline__ float lrelu(float p) { return fmaxf(p, ALPHA * p); }
__device__ __forceinline__ unsigned fenc(float f) {
    unsigned u = __float_as_uint(f);
    return (u & 0x80000000u) ? ~u : (u | 0x80000000u);   // monotone float->uint
}

__device__ __forceinline__ void gll16(const void* src, void* dst_lds) {
    __builtin_amdgcn_global_load_lds((const __attribute__((address_space(1))) void*)src,
                                     (__attribute__((address_space(3))) void*)dst_lds, 16, 0, 0);
}

// ---------------- Kernel A: h = x @ W, fused s1/s2/s2max/e2p/e2n epilogue ----------------
__global__ __launch_bounds__(256) void k_h(const float* __restrict__ x,
                                           const float* __restrict__ W,
                                           const float* __restrict__ a,
                                           float* __restrict__ h,
                                           float* __restrict__ s1,
                                           float* __restrict__ s2,
                                           unsigned* __restrict__ s2me,
                                           float* __restrict__ e2p_g,
                                           float* __restrict__ e2n_g) {
    __shared__ float Wl[FIN * FOUT];
    int t = threadIdx.x;
    #pragma unroll
    for (int i = 0; i < (FIN * FOUT) / (256 * 4); ++i) {
        int idx = (t + i * 256) * 4;
        *(float4*)&Wl[idx] = *(const float4*)&W[idx];
    }
    __syncthreads();
    int gid = blockIdx.x * 256 + t;
    int row = gid >> 6;
    int c   = gid & 63;
    float acc = 0.f;
    #pragma unroll
    for (int k = 0; k < FIN; k += 4) {
        float4 xv = *(const float4*)&x[row * FIN + k];
        acc = fmaf(xv.x, Wl[(k + 0) * FOUT + c], acc);
        acc = fmaf(xv.y, Wl[(k + 1) * FOUT + c], acc);
        acc = fmaf(xv.z, Wl[(k + 2) * FOUT + c], acc);
        acc = fmaf(xv.w, Wl[(k + 3) * FOUT + c], acc);
    }
    h[gid] = acc;
    float p1 = acc * a[c];
    float p2 = acc * a[64 + c];
    #pragma unroll
    for (int off = 32; off; off >>= 1) {
        p1 += __shfl_xor(p1, off);
        p2 += __shfl_xor(p2, off);
    }
    if (c == 0) {
        s1[row] = p1;
        s2[row] = p2;
        e2p_g[row] = __expf(p2);
        e2n_g[row] = __expf(ALPHA * p2);
        atomicMax(s2me, fenc(p2));   // order-independent -> deterministic
    }
}

// ---------------- Kernel T: hT[c][j] = bf16(h[j][c])  (64 x 8192) ----------------
__global__ __launch_bounds__(256) void k_t(const float* __restrict__ h,
                                           unsigned short* __restrict__ hT) {
    __shared__ float tile[64][65];
    int t = threadIdx.x;
    int j0 = blockIdx.x * 64;
    #pragma unroll
    for (int p = 0; p < 4; ++p) {
        int j = p * 16 + (t >> 4);
        int c4 = (t & 15) * 4;
        float4 v = *(const float4*)&h[(size_t)(j0 + j) * 64 + c4];
        tile[j][c4] = v.x; tile[j][c4 + 1] = v.y; tile[j][c4 + 2] = v.z; tile[j][c4 + 3] = v.w;
    }
    __syncthreads();
    int c = t & 63, seg = t >> 6;
    ushort8 u0, u1;
    #pragma unroll
    for (int k = 0; k < 8; ++k) u0[k] = (unsigned short)f2bf(tile[seg * 16 + k][c]);
    #pragma unroll
    for (int k = 0; k < 8; ++k) u1[k] = (unsigned short)f2bf(tile[seg * 16 + 8 + k][c]);
    unsigned short* dst = &hT[(size_t)c * N + j0 + seg * 16];
    *(ushort8*)dst = u0;
    *(ushort8*)(dst + 8) = u1;
}

// ---------------- Kernel D: all-LDS compute loop, counted-vmcnt pipeline ----------------
// ALL in-loop global traffic is global_load_lds (3 per wave per iter: 2 adj + 1 hT),
// staged distance-2 into 4-ring buffers. s_waitcnt vmcnt(6) + RAW s_barrier per iter
// (no compiler drain). Compute reads only LDS. adj chunk-XOR swizzle (src side =
// read side, rule 21). Ring-4/dist-2 skew-safe: (t+2)-(t-1)=3 != 0 mod 4.
__global__ __launch_bounds__(256, 4) void k_attn(const float* __restrict__ adj,
                                                 const unsigned short* __restrict__ hT,
                                                 const float* __restrict__ s1,
                                                 const unsigned* __restrict__ s2me,
                                                 const float* __restrict__ e2p_g,
                                                 const float* __restrict__ e2n_g,
                                                 float* __restrict__ pacc,
                                                 float* __restrict__ pden) {
    __shared__ __align__(16) char adjb[4][8192];   // [ring][localrow*128B + slot*16B]
    __shared__ __align__(16) char hbuf[4][4096];   // [ring][ldsrow*64B + slot*16B]
    __shared__ float e2p_l[JLEN];
    __shared__ float e2n_l[JLEN];

    int tid  = threadIdx.x;
    int wave = tid >> 6;
    int lane = tid & 63;
    int rb   = blockIdx.x / JS;
    int js   = blockIdx.x % JS;
    int r0   = rb * 64;
    int jb   = js * JLEN;

    int row = lane & 15;
    int kg  = lane >> 4;
    int kg8 = kg * 8;
    int lr  = wave * 16 + row;          // local row 0..63
    int r   = r0 + lr;

    // hT staging map (r10-verified): ldsrow=tid>>2, slot tid&3 holds chunk (slot-(ldsrow>>1))&3
    int ldsrow = tid >> 2;
    int cslot  = tid & 3;
    int gchunk = (cslot - (ldsrow >> 1)) & 3;
    const unsigned short* hsrc = hT + (size_t)ldsrow * N + jb + gchunk * 8;

    // adj staging map: call A rows 0..31 (first 4KB), call B rows 32..63.
    // dst slot acs of row arow holds global chunk acs^(arow&7) (XOR involution).
    int arow = tid >> 3;
    int acs  = tid & 7;
    int agc  = acs ^ (arow & 7);
    const float* asrcA = adj + (size_t)(r0 + arow) * N + jb + agc * 4;
    const float* asrcB = adj + (size_t)(r0 + 32 + arow) * N + jb + agc * 4;

    // compute-side read offsets (loop-invariant): chunks 2kg, 2kg+1 of row lr
    int offA_ = lr * 128 + (((2 * kg)     ^ (lr & 7)) * 16);
    int offB_ = lr * 128 + (((2 * kg + 1) ^ (lr & 7)) * 16);
    int bbyte = row * 64 + (((kg + (row >> 1)) & 3) * 16);   // hT read (r10-verified)

    // ---- prologue: tables to LDS, then stage tiles 0,1 (6 gll16 stay in flight)
    {
        int t2 = tid * 2;
        *(float2*)&e2p_l[t2] = *(const float2*)&e2p_g[jb + t2];
        *(float2*)&e2n_l[t2] = *(const float2*)&e2n_g[jb + t2];
    }
    gll16(asrcA,      &adjb[0][0] + tid * 16);
    gll16(asrcB,      &adjb[0][0] + 4096 + tid * 16);
    gll16(hsrc,       &hbuf[0][tid * 16]);
    gll16(asrcA + 32, &adjb[1][0] + tid * 16);
    gll16(asrcB + 32, &adjb[1][0] + 4096 + tid * 16);
    gll16(hsrc + 32,  &hbuf[1][tid * 16]);

    float s1v = s1[r];
    unsigned em = *s2me;
    float S2M = __uint_as_float((em & 0x80000000u) ? (em & 0x7fffffffu) : ~em);
    float Mv  = lrelu(s1v + S2M);
    float E1p = __expf(s1v - Mv);
    float E1n = __expf(ALPHA * s1v - Mv);
    float expC = __expf(-s1v);          // e2p[j] >= expC  <=>  s1+s2 >= 0

    asm volatile("s_waitcnt lgkmcnt(0)" ::: "memory");   // table ds_writes visible
    __builtin_amdgcn_s_barrier();

    f32x4 acc0 = {0.f, 0.f, 0.f, 0.f};
    f32x4 acc1 = {0.f, 0.f, 0.f, 0.f};
    f32x4 acc2 = {0.f, 0.f, 0.f, 0.f};
    f32x4 acc3 = {0.f, 0.f, 0.f, 0.f};
    float den = 0.f;

#define ITER(u) do {                                                           \
        int t  = 4 * pp + (u);                                                 \
        int ts = (t + 2 < NT) ? t + 2 : NT - 1;                                \
        gll16(asrcA + ts * 32, &adjb[((u) + 2) & 3][0] + tid * 16);            \
        gll16(asrcB + ts * 32, &adjb[((u) + 2) & 3][0] + 4096 + tid * 16);     \
        gll16(hsrc + ts * 32,  &hbuf[((u) + 2) & 3][tid * 16]);                \
        asm volatile("s_waitcnt vmcnt(6)" ::: "memory");                       \
        __builtin_amdgcn_sched_barrier(0);                                     \
        __builtin_amdgcn_s_barrier();                                          \
        __builtin_amdgcn_sched_barrier(0);                                     \
        int jj = t * 32 + kg8;                                                 \
        const char* ab = &adjb[(u)][0];                                        \
        float4 a0 = *(const float4*)(ab + offA_);                              \
        float4 a1 = *(const float4*)(ab + offB_);                              \
        float4 p0 = *(const float4*)&e2p_l[jj];                                \
        float4 p1 = *(const float4*)&e2p_l[jj + 4];                            \
        float4 n0 = *(const float4*)&e2n_l[jj];                                \
        float4 n1 = *(const float4*)&e2n_l[jj + 4];                            \
        float w0 = a0.x * ((p0.x >= expC) ? p0.x * E1p : n0.x * E1n);          \
        float w1 = a0.y * ((p0.y >= expC) ? p0.y * E1p : n0.y * E1n);          \
        float w2 = a0.z * ((p0.z >= expC) ? p0.z * E1p : n0.z * E1n);          \
        float w3 = a0.w * ((p0.w >= expC) ? p0.w * E1p : n0.w * E1n);          \
        float w4 = a1.x * ((p1.x >= expC) ? p1.x * E1p : n1.x * E1n);          \
        float w5 = a1.y * ((p1.y >= expC) ? p1.y * E1p : n1.y * E1n);          \
        float w6 = a1.z * ((p1.z >= expC) ? p1.z * E1p : n1.z * E1n);          \
        float w7 = a1.w * ((p1.w >= expC) ? p1.w * E1p : n1.w * E1n);          \
        den += w0 + w1 + w2 + w3 + w4 + w5 + w6 + w7;                          \
        i32x4 pk;                                                              \
        pk[0] = (int)(f2bf(w0) | (f2bf(w1) << 16));                            \
        pk[1] = (int)(f2bf(w2) | (f2bf(w3) << 16));                            \
        pk[2] = (int)(f2bf(w4) | (f2bf(w5) << 16));                            \
        pk[3] = (int)(f2bf(w6) | (f2bf(w7) << 16));                            \
        bf16x8 af = __builtin_bit_cast(bf16x8, pk);                            \
        const char* bp = &hbuf[(u)][0];                                        \
        bf16x8 b0 = *(const bf16x8*)(bp + bbyte);                              \
        bf16x8 b1 = *(const bf16x8*)(bp + bbyte + 1024);                       \
        bf16x8 b2 = *(const bf16x8*)(bp + bbyte + 2048);                       \
        bf16x8 b3 = *(const bf16x8*)(bp + bbyte + 3072);                       \
        acc0 = __builtin_amdgcn_mfma_f32_16x16x32_bf16(af, b0, acc0, 0, 0, 0); \
        acc1 = __builtin_amdgcn_mfma_f32_16x16x32_bf16(af, b1, acc1, 0, 0, 0); \
        acc2 = __builtin_amdgcn_mfma_f32_16x16x32_bf16(af, b2, acc2, 0, 0, 0); \
        acc3 = __builtin_amdgcn_mfma_f32_16x16x32_bf16(af, b3, acc3, 0, 0, 0); \
    } while (0)

    for (int pp = 0; pp < NT / 4; ++pp) {
        ITER(0);
        ITER(1);
        ITER(2);
        ITER(3);
    }
#undef ITER

    den += __shfl_xor(den, 16);
    den += __shfl_xor(den, 32);

    int r0w = r0 + wave * 16;
    #pragma unroll
    for (int q = 0; q < 4; ++q) {
        int ro = kg * 4 + q;
        size_t ob = ((size_t)js * N + r0w + ro) * 64 + row;
        pacc[ob + 0]  = acc0[q];
        pacc[ob + 16] = acc1[q];
        pacc[ob + 32] = acc2[q];
        pacc[ob + 48] = acc3[q];
    }
    if (lane < 16) pden[(size_t)js * N + r0w + lane] = den;
}

// ---------------- Kernel E: combine partials, div + elu ----------------
__global__ __launch_bounds__(256) void k_combine(const float* __restrict__ pacc,
                                                 const float* __restrict__ pden,
                                                 float* __restrict__ out) {
    int gid = blockIdx.x * 256 + threadIdx.x;
    int row = gid >> 6;
    float a = 0.f, d = 0.f;
    #pragma unroll
    for (int s = 0; s < JS; ++s) {
        a += pacc[((size_t)s * N + row) * 64 + (gid & 63)];
        d += pden[(size_t)s * N + row];
    }
    out[gid] = elu(a / d);
}

// ---------------- launch ----------------
extern "C" void kernel_launch(void* const* d_in, const int* in_sizes, int n_in,
                              void* d_out, int out_size, void* d_ws, size_t ws_size,
                              hipStream_t stream) {
    const float* x   = (const float*)d_in[0];
    const float* adj = (const float*)d_in[1];
    const float* W   = (const float*)d_in[2];
    const float* a   = (const float*)d_in[3];
    float* out = (float*)d_out;

    // ws layout (float units)
    float* ws    = (float*)d_ws;
    float* h     = ws;                               // 524288
    float* s1    = h + (size_t)N * FOUT;             // 8192
    float* s2    = s1 + N;                           // 8192
    unsigned* s2me = (unsigned*)(s2 + N);            // 64 slot
    float* e2p_g = (float*)s2me + 64;                // 8192
    float* e2n_g = e2p_g + N;                        // 8192
    float* pden  = e2n_g + N;                        // 16*8192
    unsigned short* hT = (unsigned short*)(pden + JS * N);   // 262144 float-equiv
    float* pacc  = (float*)hT + 262144;              // 16*524288

    hipMemsetAsync(s2me, 0, sizeof(unsigned), stream);   // fenc lower bound
    k_h<<<dim3((N * FOUT) / 256), dim3(256), 0, stream>>>(x, W, a, h, s1, s2, s2me, e2p_g, e2n_g);
    k_t<<<dim3(N / 64), dim3(256), 0, stream>>>(h, hT);

    k_attn<<<dim3(128 * JS), dim3(256), 0, stream>>>(adj, hT, s1, s2me, e2p_g, e2n_g, pacc, pden);
    k_combine<<<dim3((N * FOUT) / 256), dim3(256), 0, stream>>>(pacc, pden, out);
}

// Round 14
// 180.024 us; speedup vs baseline: 1.0700x; 1.0700x over previous
//
#include <hip/hip_runtime.h>
#include <math.h>

#define N 8192
#define FIN 128
#define FOUT 64
#define ALPHA 0.2f
#define JS 8
#define JLEN (N / JS)          // 1024
#define NT (JLEN / 32)         // 32 j-tiles per block

typedef __attribute__((ext_vector_type(8))) short bf16x8;
typedef __attribute__((ext_vector_type(8))) unsigned short ushort8;
typedef __attribute__((ext_vector_type(4))) float f32x4;
typedef __attribute__((ext_vector_type(4))) int i32x4;

__device__ __forceinline__ unsigned f2bf(float f) {
    unsigned int u = __float_as_uint(f);
    u += 0x7fff + ((u >> 16) & 1);          // round-to-nearest-even
    return u >> 16;
}
__device__ __forceinline__ float elu(float v) { return v > 0.f ? v : expm1f(v); }
__device__ __forceinline__ float lrelu(float p) { return fmaxf(p, ALPHA * p); }
__device__ __forceinline__ unsigned fenc(float f) {
    unsigned u = __float_as_uint(f);
    return (u & 0x80000000u) ? ~u : (u | 0x80000000u);   // monotone float->uint
}

__device__ __forceinline__ void gll16(const void* src, void* dst_lds) {
    __builtin_amdgcn_global_load_lds((const __attribute__((address_space(1))) void*)src,
                                     (__attribute__((address_space(3))) void*)dst_lds, 16, 0, 0);
}

// ---------------- Kernel A: h = x @ W, fused s1/s2/s2max/e2p/e2n epilogue ----------------
__global__ __launch_bounds__(256) void k_h(const float* __restrict__ x,
                                           const float* __restrict__ W,
                                           const float* __restrict__ a,
                                           float* __restrict__ h,
                                           float* __restrict__ s1,
                                           float* __restrict__ s2,
                                           unsigned* __restrict__ s2me,
                                           float* __restrict__ e2p_g,
                                           float* __restrict__ e2n_g) {
    __shared__ float Wl[FIN * FOUT];
    int t = threadIdx.x;
    #pragma unroll
    for (int i = 0; i < (FIN * FOUT) / (256 * 4); ++i) {
        int idx = (t + i * 256) * 4;
        *(float4*)&Wl[idx] = *(const float4*)&W[idx];
    }
    __syncthreads();
    int gid = blockIdx.x * 256 + t;
    int row = gid >> 6;
    int c   = gid & 63;
    float acc = 0.f;
    #pragma unroll
    for (int k = 0; k < FIN; k += 4) {
        float4 xv = *(const float4*)&x[row * FIN + k];
        acc = fmaf(xv.x, Wl[(k + 0) * FOUT + c], acc);
        acc = fmaf(xv.y, Wl[(k + 1) * FOUT + c], acc);
        acc = fmaf(xv.z, Wl[(k + 2) * FOUT + c], acc);
        acc = fmaf(xv.w, Wl[(k + 3) * FOUT + c], acc);
    }
    h[gid] = acc;
    float p1 = acc * a[c];
    float p2 = acc * a[64 + c];
    #pragma unroll
    for (int off = 32; off; off >>= 1) {
        p1 += __shfl_xor(p1, off);
        p2 += __shfl_xor(p2, off);
    }
    if (c == 0) {
        s1[row] = p1;
        s2[row] = p2;
        e2p_g[row] = __expf(p2);
        e2n_g[row] = __expf(ALPHA * p2);
        atomicMax(s2me, fenc(p2));   // order-independent -> deterministic
    }
}

// ---------------- Kernel T: hT[c][j] = bf16(h[j][c])  (64 x 8192) ----------------
__global__ __launch_bounds__(256) void k_t(const float* __restrict__ h,
                                           unsigned short* __restrict__ hT) {
    __shared__ float tile[64][65];
    int t = threadIdx.x;
    int j0 = blockIdx.x * 64;
    #pragma unroll
    for (int p = 0; p < 4; ++p) {
        int j = p * 16 + (t >> 4);
        int c4 = (t & 15) * 4;
        float4 v = *(const float4*)&h[(size_t)(j0 + j) * 64 + c4];
        tile[j][c4] = v.x; tile[j][c4 + 1] = v.y; tile[j][c4 + 2] = v.z; tile[j][c4 + 3] = v.w;
    }
    __syncthreads();
    int c = t & 63, seg = t >> 6;
    ushort8 u0, u1;
    #pragma unroll
    for (int k = 0; k < 8; ++k) u0[k] = (unsigned short)f2bf(tile[seg * 16 + k][c]);
    #pragma unroll
    for (int k = 0; k < 8; ++k) u1[k] = (unsigned short)f2bf(tile[seg * 16 + 8 + k][c]);
    unsigned short* dst = &hT[(size_t)c * N + j0 + seg * 16];
    *(ushort8*)dst = u0;
    *(ushort8*)(dst + 8) = u1;
}

// ---------------- Kernel D: masked softmax + attention @ h via MFMA ----------------
// r10 body VERBATIM (proven 102.8us; 3 schedule grafts all regressed): per-tile
// vmcnt(0)+syncthreads drain, hT double-buffer via global_load_lds, separable-exp
// weights from L2/LDS tables. Only change: JS 16->8 (1024 blocks = exactly 4/CU,
// halves partial traffic).
__global__ __launch_bounds__(256, 4) void k_attn(const float* __restrict__ adj,
                                                 const unsigned short* __restrict__ hT,
                                                 const float* __restrict__ s1,
                                                 const unsigned* __restrict__ s2me,
                                                 const float* __restrict__ e2p_g,
                                                 const float* __restrict__ e2n_g,
                                                 float* __restrict__ pacc,
                                                 float* __restrict__ pden) {
    __shared__ __align__(16) char hbuf[2][4096];   // [buf][ldsrow*64B + slot*16B]
    __shared__ float e2p_l[JLEN];
    __shared__ float e2n_l[JLEN];

    int tid  = threadIdx.x;
    int wave = tid >> 6;
    int lane = tid & 63;
    int rb   = blockIdx.x / JS;
    int js   = blockIdx.x % JS;
    int r0   = rb * 64;
    int jb   = js * JLEN;

    int row = lane & 15;
    int kg  = lane >> 4;
    int kg8 = kg * 8;
    int r   = r0 + wave * 16 + row;

    // staging map (r10-verified): ldsrow = tid>>2, slot tid&3 holds global chunk
    // (slot - (ldsrow>>1))&3 ; read swizzle (kg + (row>>1))&3.
    int ldsrow = tid >> 2;
    int cslot  = tid & 3;
    int gchunk = (cslot - (ldsrow >> 1)) & 3;
    const unsigned short* hsrc = hT + (size_t)ldsrow * N + jb + gchunk * 8;
    char* ldst0 = &hbuf[0][tid * 16];
    char* ldst1 = &hbuf[1][tid * 16];

    // ---- prologue: stage tile 0 + tables
    gll16(hsrc, ldst0);
    {
        int t4 = tid * 4;
        *(float4*)&e2p_l[t4] = *(const float4*)&e2p_g[jb + t4];
        *(float4*)&e2n_l[t4] = *(const float4*)&e2n_g[jb + t4];
    }
    float s1v = s1[r];
    unsigned em = *s2me;
    float S2M = __uint_as_float((em & 0x80000000u) ? (em & 0x7fffffffu) : ~em);
    float Mv  = lrelu(s1v + S2M);
    float E1p = __expf(s1v - Mv);
    float E1n = __expf(ALPHA * s1v - Mv);
    float expC = __expf(-s1v);          // e2p[j] >= expC  <=>  s1+s2 >= 0

    asm volatile("s_waitcnt vmcnt(0)" ::: "memory");
    __syncthreads();

    f32x4 acc0 = {0.f, 0.f, 0.f, 0.f};
    f32x4 acc1 = {0.f, 0.f, 0.f, 0.f};
    f32x4 acc2 = {0.f, 0.f, 0.f, 0.f};
    f32x4 acc3 = {0.f, 0.f, 0.f, 0.f};
    float den = 0.f;

    const size_t rbase = (size_t)r * N + jb;
    int bbyte = row * 64 + (((kg + (row >> 1)) & 3) * 16);   // swizzled read offset

    #pragma unroll 2
    for (int t = 0; t < NT; ++t) {
        if (t + 1 < NT)
            gll16(hsrc + (t + 1) * 32, ((t + 1) & 1) ? ldst1 : ldst0);

        int jj = t * 32 + kg8;
        float4 a0 = *(const float4*)&adj[rbase + jj];
        float4 a1 = *(const float4*)&adj[rbase + jj + 4];
        float4 p0 = *(const float4*)&e2p_l[jj];
        float4 p1 = *(const float4*)&e2p_l[jj + 4];
        float4 n0 = *(const float4*)&e2n_l[jj];
        float4 n1 = *(const float4*)&e2n_l[jj + 4];

        float w0 = a0.x * ((p0.x >= expC) ? p0.x * E1p : n0.x * E1n);
        float w1 = a0.y * ((p0.y >= expC) ? p0.y * E1p : n0.y * E1n);
        float w2 = a0.z * ((p0.z >= expC) ? p0.z * E1p : n0.z * E1n);
        float w3 = a0.w * ((p0.w >= expC) ? p0.w * E1p : n0.w * E1n);
        float w4 = a1.x * ((p1.x >= expC) ? p1.x * E1p : n1.x * E1n);
        float w5 = a1.y * ((p1.y >= expC) ? p1.y * E1p : n1.y * E1n);
        float w6 = a1.z * ((p1.z >= expC) ? p1.z * E1p : n1.z * E1n);
        float w7 = a1.w * ((p1.w >= expC) ? p1.w * E1p : n1.w * E1n);
        den += w0 + w1 + w2 + w3 + w4 + w5 + w6 + w7;

        i32x4 pk;
        pk[0] = (int)(f2bf(w0) | (f2bf(w1) << 16));
        pk[1] = (int)(f2bf(w2) | (f2bf(w3) << 16));
        pk[2] = (int)(f2bf(w4) | (f2bf(w5) << 16));
        pk[3] = (int)(f2bf(w6) | (f2bf(w7) << 16));
        bf16x8 af = __builtin_bit_cast(bf16x8, pk);

        const char* bb = (t & 1) ? &hbuf[1][0] : &hbuf[0][0];
        bf16x8 b0 = *(const bf16x8*)(bb + bbyte);
        bf16x8 b1 = *(const bf16x8*)(bb + bbyte + 1024);
        bf16x8 b2 = *(const bf16x8*)(bb + bbyte + 2048);
        bf16x8 b3 = *(const bf16x8*)(bb + bbyte + 3072);
        acc0 = __builtin_amdgcn_mfma_f32_16x16x32_bf16(af, b0, acc0, 0, 0, 0);
        acc1 = __builtin_amdgcn_mfma_f32_16x16x32_bf16(af, b1, acc1, 0, 0, 0);
        acc2 = __builtin_amdgcn_mfma_f32_16x16x32_bf16(af, b2, acc2, 0, 0, 0);
        acc3 = __builtin_amdgcn_mfma_f32_16x16x32_bf16(af, b3, acc3, 0, 0, 0);

        asm volatile("s_waitcnt vmcnt(0)" ::: "memory");
        __syncthreads();
    }

    den += __shfl_xor(den, 16);
    den += __shfl_xor(den, 32);

    int r0w = r0 + wave * 16;
    #pragma unroll
    for (int q = 0; q < 4; ++q) {
        int ro = kg * 4 + q;
        size_t ob = ((size_t)js * N + r0w + ro) * 64 + row;
        pacc[ob + 0]  = acc0[q];
        pacc[ob + 16] = acc1[q];
        pacc[ob + 32] = acc2[q];
        pacc[ob + 48] = acc3[q];
    }
    if (lane < 16) pden[(size_t)js * N + r0w + lane] = den;
}

// ---------------- Kernel E: combine partials, div + elu ----------------
__global__ __launch_bounds__(256) void k_combine(const float* __restrict__ pacc,
                                                 const float* __restrict__ pden,
                                                 float* __restrict__ out) {
    int gid = blockIdx.x * 256 + threadIdx.x;
    int row = gid >> 6;
    float a = 0.f, d = 0.f;
    #pragma unroll
    for (int s = 0; s < JS; ++s) {
        a += pacc[((size_t)s * N + row) * 64 + (gid & 63)];
        d += pden[(size_t)s * N + row];
    }
    out[gid] = elu(a / d);
}

// ---------------- launch ----------------
extern "C" void kernel_launch(void* const* d_in, const int* in_sizes, int n_in,
                              void* d_out, int out_size, void* d_ws, size_t ws_size,
                              hipStream_t stream) {
    const float* x   = (const float*)d_in[0];
    const float* adj = (const float*)d_in[1];
    const float* W   = (const float*)d_in[2];
    const float* a   = (const float*)d_in[3];
    float* out = (float*)d_out;

    // ws layout (float units)
    float* ws    = (float*)d_ws;
    float* h     = ws;                               // 524288
    float* s1    = h + (size_t)N * FOUT;             // 8192
    float* s2    = s1 + N;                           // 8192
    unsigned* s2me = (unsigned*)(s2 + N);            // 64 slot
    float* e2p_g = (float*)s2me + 64;                // 8192
    float* e2n_g = e2p_g + N;                        // 8192
    float* pden  = e2n_g + N;                        // 8*8192
    unsigned short* hT = (unsigned short*)(pden + JS * N);   // 262144 float-equiv
    float* pacc  = (float*)hT + 262144;              // 8*524288

    hipMemsetAsync(s2me, 0, sizeof(unsigned), stream);   // fenc lower bound
    k_h<<<dim3((N * FOUT) / 256), dim3(256), 0, stream>>>(x, W, a, h, s1, s2, s2me, e2p_g, e2n_g);
    k_t<<<dim3(N / 64), dim3(256), 0, stream>>>(h, hT);

    k_attn<<<dim3(128 * JS), dim3(256), 0, stream>>>(adj, hT, s1, s2me, e2p_g, e2n_g, pacc, pden);
    k_combine<<<dim3((N * FOUT) / 256), dim3(256), 0, stream>>>(pacc, pden, out);
}

// Round 15
// 122.642 us; speedup vs baseline: 1.5707x; 1.4679x over previous
//
#include <hip/hip_runtime.h>
#include <math.h>

#define N 8192
#define FIN 128
#define FOUT 64
#define ALPHA 0.2f
#define JS 16
#define JLEN (N / JS)          // 512
#define NT (JLEN / 32)         // 16 j-tiles per block

typedef __attribute__((ext_vector_type(8))) short bf16x8;
typedef __attribute__((ext_vector_type(8))) unsigned short ushort8;
typedef __attribute__((ext_vector_type(4))) float f32x4;
typedef __attribute__((ext_vector_type(4))) int i32x4;

__device__ __forceinline__ unsigned f2bf(float f) {
    unsigned int u = __float_as_uint(f);
    u += 0x7fff + ((u >> 16) & 1);          // round-to-nearest-even
    return u >> 16;
}
__device__ __forceinline__ float elu(float v) { return v > 0.f ? v : expm1f(v); }
__device__ __forceinline__ float lrelu(float p) { return fmaxf(p, ALPHA * p); }
__device__ __forceinline__ unsigned fenc(float f) {
    unsigned u = __float_as_uint(f);
    return (u & 0x80000000u) ? ~u : (u | 0x80000000u);   // monotone float->uint
}

__device__ __forceinline__ void gll16(const void* src, void* dst_lds) {
    __builtin_amdgcn_global_load_lds((const __attribute__((address_space(1))) void*)src,
                                     (__attribute__((address_space(3))) void*)dst_lds, 16, 0, 0);
}

// ---------------- Kernel A: h = x @ W, fused s1/s2 epilogue (NO single-address atomic:
// 8192 same-address atomicMax measured +77us serialization r14/r13/r11/r3) ----------------
__global__ __launch_bounds__(256) void k_h(const float* __restrict__ x,
                                           const float* __restrict__ W,
                                           const float* __restrict__ a,
                                           float* __restrict__ h,
                                           float* __restrict__ s1,
                                           float* __restrict__ s2) {
    __shared__ float Wl[FIN * FOUT];
    int t = threadIdx.x;
    #pragma unroll
    for (int i = 0; i < (FIN * FOUT) / (256 * 4); ++i) {
        int idx = (t + i * 256) * 4;
        *(float4*)&Wl[idx] = *(const float4*)&W[idx];
    }
    __syncthreads();
    int gid = blockIdx.x * 256 + t;
    int row = gid >> 6;
    int c   = gid & 63;
    float acc = 0.f;
    #pragma unroll
    for (int k = 0; k < FIN; k += 4) {
        float4 xv = *(const float4*)&x[row * FIN + k];
        acc = fmaf(xv.x, Wl[(k + 0) * FOUT + c], acc);
        acc = fmaf(xv.y, Wl[(k + 1) * FOUT + c], acc);
        acc = fmaf(xv.z, Wl[(k + 2) * FOUT + c], acc);
        acc = fmaf(xv.w, Wl[(k + 3) * FOUT + c], acc);
    }
    h[gid] = acc;
    float p1 = acc * a[c];
    float p2 = acc * a[64 + c];
    #pragma unroll
    for (int off = 32; off; off >>= 1) {
        p1 += __shfl_xor(p1, off);
        p2 += __shfl_xor(p2, off);
    }
    if (c == 0) { s1[row] = p1; s2[row] = p2; }
}

// ---------------- Kernel T: hT transpose->bf16, fused e2p/e2n tables + s2max
// (per-block wave-reduce, ONE atomicMax per block = 128 total, ~1us) ----------------
__global__ __launch_bounds__(256) void k_t(const float* __restrict__ h,
                                           const float* __restrict__ s2,
                                           unsigned short* __restrict__ hT,
                                           float* __restrict__ e2p_g,
                                           float* __restrict__ e2n_g,
                                           unsigned* __restrict__ s2me) {
    __shared__ float tile[64][65];
    int t = threadIdx.x;
    int j0 = blockIdx.x * 64;
    #pragma unroll
    for (int p = 0; p < 4; ++p) {
        int j = p * 16 + (t >> 4);
        int c4 = (t & 15) * 4;
        float4 v = *(const float4*)&h[(size_t)(j0 + j) * 64 + c4];
        tile[j][c4] = v.x; tile[j][c4 + 1] = v.y; tile[j][c4 + 2] = v.z; tile[j][c4 + 3] = v.w;
    }
    __syncthreads();
    int c = t & 63, seg = t >> 6;
    ushort8 u0, u1;
    #pragma unroll
    for (int k = 0; k < 8; ++k) u0[k] = (unsigned short)f2bf(tile[seg * 16 + k][c]);
    #pragma unroll
    for (int k = 0; k < 8; ++k) u1[k] = (unsigned short)f2bf(tile[seg * 16 + 8 + k][c]);
    unsigned short* dst = &hT[(size_t)c * N + j0 + seg * 16];
    *(ushort8*)dst = u0;
    *(ushort8*)(dst + 8) = u1;
    if (t < 64) {              // wave 0 exactly: uniform branch per wave
        int j = j0 + t;
        float s = s2[j];
        e2p_g[j] = __expf(s);
        e2n_g[j] = __expf(ALPHA * s);
        float m = s;
        #pragma unroll
        for (int off = 32; off; off >>= 1) m = fmaxf(m, __shfl_xor(m, off));
        if (t == 0) atomicMax(s2me, fenc(m));
    }
}

// ---------------- Kernel D: BARRIER-FREE wave-private pipelined attn ----------------
// Each wave owns 2 private 4KB hT buffers, staged with 4 gll16 per tile; adj tile
// prefetched into regs. Per-tile group = 6 vmem ops (pinned contiguous by
// sched_barrier). Loop sync = per-wave s_waitcnt vmcnt(6), dist-2 prefetch,
// ZERO barriers in loop (r11-r13 failures all kept block barriers).
__global__ __launch_bounds__(256, 4) void k_attn(const float* __restrict__ adj,
                                                 const unsigned short* __restrict__ hT,
                                                 const float* __restrict__ s1,
                                                 const unsigned* __restrict__ s2me,
                                                 const float* __restrict__ e2p_g,
                                                 const float* __restrict__ e2n_g,
                                                 float* __restrict__ pacc,
                                                 float* __restrict__ pden) {
    __shared__ __align__(16) char hbuf[4][2][4096];   // [wave][buf][ldsrow*64B+slot*16B]
    __shared__ float e2p_l[JLEN];
    __shared__ float e2n_l[JLEN];

    int tid  = threadIdx.x;
    int wave = tid >> 6;
    int lane = tid & 63;
    int rb   = blockIdx.x / JS;
    int js   = blockIdx.x % JS;
    int r0   = rb * 64;
    int jb   = js * JLEN;

    int row = lane & 15;
    int kg  = lane >> 4;
    int kg8 = kg * 8;
    int r   = r0 + wave * 16 + row;

    // tables + scalars BEFORE the single barrier (its auto-drain then costs nothing)
    {
        int t2 = tid * 2;
        *(float2*)&e2p_l[t2] = *(const float2*)&e2p_g[jb + t2];
        *(float2*)&e2n_l[t2] = *(const float2*)&e2n_g[jb + t2];
    }
    float s1v = s1[r];
    unsigned em = *s2me;
    float S2M = __uint_as_float((em & 0x80000000u) ? (em & 0x7fffffffu) : ~em);
    float Mv  = lrelu(s1v + S2M);
    float E1p = __expf(s1v - Mv);
    float E1n = __expf(ALPHA * s1v - Mv);
    float expC = __expf(-s1v);          // e2p[j] >= expC  <=>  s1+s2 >= 0
    __syncthreads();

    // wave-private staging source (r10-verified layout, q-independent chunk swizzle)
    int subrow = lane >> 2;                       // 0..15
    int slot   = lane & 3;
    int gchunk = (slot - (lane >> 3)) & 3;
    const unsigned short* hs = hT + (size_t)subrow * N + jb + gchunk * 8;
    char* hw0 = &hbuf[wave][0][0];
    char* hw1 = &hbuf[wave][1][0];

#define STAGE(bufp, tt) do {                                                   \
        gll16(hs + (size_t)0 * 16 * N + (tt) * 32, (bufp) + 0 * 1024 + lane * 16); \
        gll16(hs + (size_t)1 * 16 * N + (tt) * 32, (bufp) + 1 * 1024 + lane * 16); \
        gll16(hs + (size_t)2 * 16 * N + (tt) * 32, (bufp) + 2 * 1024 + lane * 16); \
        gll16(hs + (size_t)3 * 16 * N + (tt) * 32, (bufp) + 3 * 1024 + lane * 16); \
    } while (0)

    const size_t rbase = (size_t)r * N + jb;
    int bbyte = row * 64 + (((kg + (row >> 1)) & 3) * 16);   // swizzled read offset

    // prologue: tile0 group (6 ops), tile1 group (6 ops), order pinned
    float4 A0 = *(const float4*)&adj[rbase + kg8];
    float4 A1 = *(const float4*)&adj[rbase + kg8 + 4];
    STAGE(hw0, 0);
    __builtin_amdgcn_sched_barrier(0);
    float4 B0 = *(const float4*)&adj[rbase + 32 + kg8];
    float4 B1 = *(const float4*)&adj[rbase + 32 + kg8 + 4];
    STAGE(hw1, 1);
    __builtin_amdgcn_sched_barrier(0);

    f32x4 acc0 = {0.f, 0.f, 0.f, 0.f};
    f32x4 acc1 = {0.f, 0.f, 0.f, 0.f};
    f32x4 acc2 = {0.f, 0.f, 0.f, 0.f};
    f32x4 acc3 = {0.f, 0.f, 0.f, 0.f};
    float den = 0.f;

#define ITER(u, C0, C1, BUFP) do {                                             \
        int t = 2 * p + (u);                                                   \
        asm volatile("s_waitcnt vmcnt(6)" ::: "memory");                       \
        __builtin_amdgcn_sched_barrier(0);                                     \
        int jj = t * 32 + kg8;                                                 \
        float4 p0 = *(const float4*)&e2p_l[jj];                                \
        float4 p1 = *(const float4*)&e2p_l[jj + 4];                            \
        float4 n0 = *(const float4*)&e2n_l[jj];                                \
        float4 n1 = *(const float4*)&e2n_l[jj + 4];                            \
        float w0 = C0.x * ((p0.x >= expC) ? p0.x * E1p : n0.x * E1n);          \
        float w1 = C0.y * ((p0.y >= expC) ? p0.y * E1p : n0.y * E1n);          \
        float w2 = C0.z * ((p0.z >= expC) ? p0.z * E1p : n0.z * E1n);          \
        float w3 = C0.w * ((p0.w >= expC) ? p0.w * E1p : n0.w * E1n);          \
        float w4 = C1.x * ((p1.x >= expC) ? p1.x * E1p : n1.x * E1n);          \
        float w5 = C1.y * ((p1.y >= expC) ? p1.y * E1p : n1.y * E1n);          \
        float w6 = C1.z * ((p1.z >= expC) ? p1.z * E1p : n1.z * E1n);          \
        float w7 = C1.w * ((p1.w >= expC) ? p1.w * E1p : n1.w * E1n);          \
        den += w0 + w1 + w2 + w3 + w4 + w5 + w6 + w7;                          \
        i32x4 pk;                                                              \
        pk[0] = (int)(f2bf(w0) | (f2bf(w1) << 16));                            \
        pk[1] = (int)(f2bf(w2) | (f2bf(w3) << 16));                            \
        pk[2] = (int)(f2bf(w4) | (f2bf(w5) << 16));                            \
        pk[3] = (int)(f2bf(w6) | (f2bf(w7) << 16));                            \
        bf16x8 af = __builtin_bit_cast(bf16x8, pk);                            \
        bf16x8 b0 = *(const bf16x8*)((BUFP) + bbyte);                          \
        bf16x8 b1 = *(const bf16x8*)((BUFP) + bbyte + 1024);                   \
        bf16x8 b2 = *(const bf16x8*)((BUFP) + bbyte + 2048);                   \
        bf16x8 b3 = *(const bf16x8*)((BUFP) + bbyte + 3072);                   \
        acc0 = __builtin_amdgcn_mfma_f32_16x16x32_bf16(af, b0, acc0, 0, 0, 0); \
        acc1 = __builtin_amdgcn_mfma_f32_16x16x32_bf16(af, b1, acc1, 0, 0, 0); \
        acc2 = __builtin_amdgcn_mfma_f32_16x16x32_bf16(af, b2, acc2, 0, 0, 0); \
        acc3 = __builtin_amdgcn_mfma_f32_16x16x32_bf16(af, b3, acc3, 0, 0, 0); \
        __builtin_amdgcn_sched_barrier(0);                                     \
        int ts = (t + 2 < NT) ? t + 2 : NT - 1;                                \
        C0 = *(const float4*)&adj[rbase + ts * 32 + kg8];                      \
        C1 = *(const float4*)&adj[rbase + ts * 32 + kg8 + 4];                  \
        STAGE(BUFP, ts);                                                       \
        __builtin_amdgcn_sched_barrier(0);                                     \
    } while (0)

    for (int p = 0; p < NT / 2; ++p) {
        ITER(0, A0, A1, hw0);
        ITER(1, B0, B1, hw1);
    }
#undef ITER
#undef STAGE

    den += __shfl_xor(den, 16);
    den += __shfl_xor(den, 32);

    int r0w = r0 + wave * 16;
    #pragma unroll
    for (int q = 0; q < 4; ++q) {
        int ro = kg * 4 + q;
        size_t ob = ((size_t)js * N + r0w + ro) * 64 + row;
        pacc[ob + 0]  = acc0[q];
        pacc[ob + 16] = acc1[q];
        pacc[ob + 32] = acc2[q];
        pacc[ob + 48] = acc3[q];
    }
    if (lane < 16) pden[(size_t)js * N + r0w + lane] = den;
}

// ---------------- Kernel E: combine partials, div + elu ----------------
__global__ __launch_bounds__(256) void k_combine(const float* __restrict__ pacc,
                                                 const float* __restrict__ pden,
                                                 float* __restrict__ out) {
    int gid = blockIdx.x * 256 + threadIdx.x;
    int row = gid >> 6;
    float a = 0.f, d = 0.f;
    #pragma unroll
    for (int s = 0; s < JS; ++s) {
        a += pacc[((size_t)s * N + row) * 64 + (gid & 63)];
        d += pden[(size_t)s * N + row];
    }
    out[gid] = elu(a / d);
}

// ---------------- launch ----------------
extern "C" void kernel_launch(void* const* d_in, const int* in_sizes, int n_in,
                              void* d_out, int out_size, void* d_ws, size_t ws_size,
                              hipStream_t stream) {
    const float* x   = (const float*)d_in[0];
    const float* adj = (const float*)d_in[1];
    const float* W   = (const float*)d_in[2];
    const float* a   = (const float*)d_in[3];
    float* out = (float*)d_out;

    // ws layout (float units)
    float* ws    = (float*)d_ws;
    float* h     = ws;                               // 524288
    float* s1    = h + (size_t)N * FOUT;             // 8192
    float* s2    = s1 + N;                           // 8192
    unsigned* s2me = (unsigned*)(s2 + N);            // 64 slot
    float* e2p_g = (float*)s2me + 64;                // 8192
    float* e2n_g = e2p_g + N;                        // 8192
    float* pden  = e2n_g + N;                        // 16*8192
    unsigned short* hT = (unsigned short*)(pden + JS * N);   // 262144 float-equiv
    float* pacc  = (float*)hT + 262144;              // 16*524288

    hipMemsetAsync(s2me, 0, sizeof(unsigned), stream);   // fenc lower bound
    k_h<<<dim3((N * FOUT) / 256), dim3(256), 0, stream>>>(x, W, a, h, s1, s2);
    k_t<<<dim3(N / 64), dim3(256), 0, stream>>>(h, s2, hT, e2p_g, e2n_g, s2me);

    k_attn<<<dim3(128 * JS), dim3(256), 0, stream>>>(adj, hT, s1, s2me, e2p_g, e2n_g, pacc, pden);
    k_combine<<<dim3((N * FOUT) / 256), dim3(256), 0, stream>>>(pacc, pden, out);
}

// Round 16
// 102.228 us; speedup vs baseline: 1.8843x; 1.1997x over previous
//
#include <hip/hip_runtime.h>
#include <math.h>

#define N 8192
#define FIN 128
#define FOUT 64
#define ALPHA 0.2f
#define JS 16
#define JLEN (N / JS)          // 512
#define NT (JLEN / 32)         // 16 j-tiles per block

typedef __attribute__((ext_vector_type(8))) short bf16x8;
typedef __attribute__((ext_vector_type(8))) unsigned short ushort8;
typedef __attribute__((ext_vector_type(4))) float f32x4;
typedef __attribute__((ext_vector_type(4))) int i32x4;

__device__ __forceinline__ unsigned f2bf(float f) {
    unsigned int u = __float_as_uint(f);
    u += 0x7fff + ((u >> 16) & 1);          // round-to-nearest-even
    return u >> 16;
}
__device__ __forceinline__ float elu(float v) { return v > 0.f ? v : expm1f(v); }
__device__ __forceinline__ float lrelu(float p) { return fmaxf(p, ALPHA * p); }
__device__ __forceinline__ unsigned fenc(float f) {
    unsigned u = __float_as_uint(f);
    return (u & 0x80000000u) ? ~u : (u | 0x80000000u);   // monotone float->uint
}

__device__ __forceinline__ void gll16(const void* src, void* dst_lds) {
    __builtin_amdgcn_global_load_lds((const __attribute__((address_space(1))) void*)src,
                                     (__attribute__((address_space(3))) void*)dst_lds, 16, 0, 0);
}

// ---------------- Kernel A: h = x @ W, fused s1/s2 epilogue ----------------
// NO single-address per-row atomic (8192 same-address atomicMax = +77us, r14/r13/r11/r3).
__global__ __launch_bounds__(256) void k_h(const float* __restrict__ x,
                                           const float* __restrict__ W,
                                           const float* __restrict__ a,
                                           float* __restrict__ h,
                                           float* __restrict__ s1,
                                           float* __restrict__ s2) {
    __shared__ float Wl[FIN * FOUT];
    int t = threadIdx.x;
    #pragma unroll
    for (int i = 0; i < (FIN * FOUT) / (256 * 4); ++i) {
        int idx = (t + i * 256) * 4;
        *(float4*)&Wl[idx] = *(const float4*)&W[idx];
    }
    __syncthreads();
    int gid = blockIdx.x * 256 + t;
    int row = gid >> 6;
    int c   = gid & 63;
    float acc = 0.f;
    #pragma unroll
    for (int k = 0; k < FIN; k += 4) {
        float4 xv = *(const float4*)&x[row * FIN + k];
        acc = fmaf(xv.x, Wl[(k + 0) * FOUT + c], acc);
        acc = fmaf(xv.y, Wl[(k + 1) * FOUT + c], acc);
        acc = fmaf(xv.z, Wl[(k + 2) * FOUT + c], acc);
        acc = fmaf(xv.w, Wl[(k + 3) * FOUT + c], acc);
    }
    h[gid] = acc;
    float p1 = acc * a[c];
    float p2 = acc * a[64 + c];
    #pragma unroll
    for (int off = 32; off; off >>= 1) {
        p1 += __shfl_xor(p1, off);
        p2 += __shfl_xor(p2, off);
    }
    if (c == 0) { s1[row] = p1; s2[row] = p2; }
}

// ---------------- Kernel T: hT transpose->bf16, fused e2p/e2n tables + s2max ----------------
// s2max: per-block wave-reduce + ONE atomicMax per block (128 total ~1us) — proven r15.
__global__ __launch_bounds__(256) void k_t(const float* __restrict__ h,
                                           const float* __restrict__ s2,
                                           unsigned short* __restrict__ hT,
                                           float* __restrict__ e2p_g,
                                           float* __restrict__ e2n_g,
                                           unsigned* __restrict__ s2me) {
    __shared__ float tile[64][65];
    int t = threadIdx.x;
    int j0 = blockIdx.x * 64;
    #pragma unroll
    for (int p = 0; p < 4; ++p) {
        int j = p * 16 + (t >> 4);
        int c4 = (t & 15) * 4;
        float4 v = *(const float4*)&h[(size_t)(j0 + j) * 64 + c4];
        tile[j][c4] = v.x; tile[j][c4 + 1] = v.y; tile[j][c4 + 2] = v.z; tile[j][c4 + 3] = v.w;
    }
    __syncthreads();
    int c = t & 63, seg = t >> 6;
    ushort8 u0, u1;
    #pragma unroll
    for (int k = 0; k < 8; ++k) u0[k] = (unsigned short)f2bf(tile[seg * 16 + k][c]);
    #pragma unroll
    for (int k = 0; k < 8; ++k) u1[k] = (unsigned short)f2bf(tile[seg * 16 + 8 + k][c]);
    unsigned short* dst = &hT[(size_t)c * N + j0 + seg * 16];
    *(ushort8*)dst = u0;
    *(ushort8*)(dst + 8) = u1;
    if (t < 64) {              // wave 0 exactly: uniform branch
        int j = j0 + t;
        float s = s2[j];
        e2p_g[j] = __expf(s);
        e2n_g[j] = __expf(ALPHA * s);
        float m = s;
        #pragma unroll
        for (int off = 32; off; off >>= 1) m = fmaxf(m, __shfl_xor(m, off));
        if (t == 0) atomicMax(s2me, fenc(m));
    }
}

// ---------------- Kernel D: masked softmax + attention @ h via MFMA ----------------
// r10 BYTE-IDENTICAL body (proven 102.8us total; 6 schedule experiments all lost to it):
// separable-exp weights, hT 2-deep LDS double-buffer via global_load_lds, per-tile
// vmcnt(0)+__syncthreads drain. DO NOT TOUCH.
__global__ __launch_bounds__(256, 4) void k_attn(const float* __restrict__ adj,
                                                 const unsigned short* __restrict__ hT,
                                                 const float* __restrict__ s1,
                                                 const unsigned* __restrict__ s2me,
                                                 const float* __restrict__ e2p_g,
                                                 const float* __restrict__ e2n_g,
                                                 float* __restrict__ pacc,
                                                 float* __restrict__ pden) {
    __shared__ __align__(16) char hbuf[2][4096];   // [buf][ldsrow*64B + slot*16B]
    __shared__ float e2p_l[JLEN];
    __shared__ float e2n_l[JLEN];

    int tid  = threadIdx.x;
    int wave = tid >> 6;
    int lane = tid & 63;
    int rb   = blockIdx.x / JS;
    int js   = blockIdx.x % JS;
    int r0   = rb * 64;
    int jb   = js * JLEN;

    int row = lane & 15;
    int kg  = lane >> 4;
    int kg8 = kg * 8;
    int r   = r0 + wave * 16 + row;

    // staging map (r10-verified): ldsrow = tid>>2, slot tid&3 holds global chunk
    // (slot - (ldsrow>>1))&3 ; read swizzle (kg + (row>>1))&3.
    int ldsrow = tid >> 2;
    int cslot  = tid & 3;
    int gchunk = (cslot - (ldsrow >> 1)) & 3;
    const unsigned short* hsrc = hT + (size_t)ldsrow * N + jb + gchunk * 8;
    char* ldst0 = &hbuf[0][tid * 16];
    char* ldst1 = &hbuf[1][tid * 16];

    // ---- prologue: stage tile 0 + tables
    gll16(hsrc, ldst0);
    {
        int t2 = tid * 2;
        *(float2*)&e2p_l[t2] = *(const float2*)&e2p_g[jb + t2];
        *(float2*)&e2n_l[t2] = *(const float2*)&e2n_g[jb + t2];
    }
    float s1v = s1[r];
    unsigned em = *s2me;
    float S2M = __uint_as_float((em & 0x80000000u) ? (em & 0x7fffffffu) : ~em);
    float Mv  = lrelu(s1v + S2M);
    float E1p = __expf(s1v - Mv);
    float E1n = __expf(ALPHA * s1v - Mv);
    float expC = __expf(-s1v);          // e2p[j] >= expC  <=>  s1+s2 >= 0

    asm volatile("s_waitcnt vmcnt(0)" ::: "memory");
    __syncthreads();

    f32x4 acc0 = {0.f, 0.f, 0.f, 0.f};
    f32x4 acc1 = {0.f, 0.f, 0.f, 0.f};
    f32x4 acc2 = {0.f, 0.f, 0.f, 0.f};
    f32x4 acc3 = {0.f, 0.f, 0.f, 0.f};
    float den = 0.f;

    const size_t rbase = (size_t)r * N + jb;
    int bbyte = row * 64 + (((kg + (row >> 1)) & 3) * 16);   // swizzled read offset

    #pragma unroll 2
    for (int t = 0; t < NT; ++t) {
        if (t + 1 < NT)
            gll16(hsrc + (t + 1) * 32, ((t + 1) & 1) ? ldst1 : ldst0);

        int jj = t * 32 + kg8;
        float4 a0 = *(const float4*)&adj[rbase + jj];
        float4 a1 = *(const float4*)&adj[rbase + jj + 4];
        float4 p0 = *(const float4*)&e2p_l[jj];
        float4 p1 = *(const float4*)&e2p_l[jj + 4];
        float4 n0 = *(const float4*)&e2n_l[jj];
        float4 n1 = *(const float4*)&e2n_l[jj + 4];

        float w0 = a0.x * ((p0.x >= expC) ? p0.x * E1p : n0.x * E1n);
        float w1 = a0.y * ((p0.y >= expC) ? p0.y * E1p : n0.y * E1n);
        float w2 = a0.z * ((p0.z >= expC) ? p0.z * E1p : n0.z * E1n);
        float w3 = a0.w * ((p0.w >= expC) ? p0.w * E1p : n0.w * E1n);
        float w4 = a1.x * ((p1.x >= expC) ? p1.x * E1p : n1.x * E1n);
        float w5 = a1.y * ((p1.y >= expC) ? p1.y * E1p : n1.y * E1n);
        float w6 = a1.z * ((p1.z >= expC) ? p1.z * E1p : n1.z * E1n);
        float w7 = a1.w * ((p1.w >= expC) ? p1.w * E1p : n1.w * E1n);
        den += w0 + w1 + w2 + w3 + w4 + w5 + w6 + w7;

        i32x4 pk;
        pk[0] = (int)(f2bf(w0) | (f2bf(w1) << 16));
        pk[1] = (int)(f2bf(w2) | (f2bf(w3) << 16));
        pk[2] = (int)(f2bf(w4) | (f2bf(w5) << 16));
        pk[3] = (int)(f2bf(w6) | (f2bf(w7) << 16));
        bf16x8 af = __builtin_bit_cast(bf16x8, pk);

        const char* bb = (t & 1) ? &hbuf[1][0] : &hbuf[0][0];
        bf16x8 b0 = *(const bf16x8*)(bb + bbyte);
        bf16x8 b1 = *(const bf16x8*)(bb + bbyte + 1024);
        bf16x8 b2 = *(const bf16x8*)(bb + bbyte + 2048);
        bf16x8 b3 = *(const bf16x8*)(bb + bbyte + 3072);
        acc0 = __builtin_amdgcn_mfma_f32_16x16x32_bf16(af, b0, acc0, 0, 0, 0);
        acc1 = __builtin_amdgcn_mfma_f32_16x16x32_bf16(af, b1, acc1, 0, 0, 0);
        acc2 = __builtin_amdgcn_mfma_f32_16x16x32_bf16(af, b2, acc2, 0, 0, 0);
        acc3 = __builtin_amdgcn_mfma_f32_16x16x32_bf16(af, b3, acc3, 0, 0, 0);

        asm volatile("s_waitcnt vmcnt(0)" ::: "memory");
        __syncthreads();
    }

    den += __shfl_xor(den, 16);
    den += __shfl_xor(den, 32);

    int r0w = r0 + wave * 16;
    #pragma unroll
    for (int q = 0; q < 4; ++q) {
        int ro = kg * 4 + q;
        size_t ob = ((size_t)js * N + r0w + ro) * 64 + row;
        pacc[ob + 0]  = acc0[q];
        pacc[ob + 16] = acc1[q];
        pacc[ob + 32] = acc2[q];
        pacc[ob + 48] = acc3[q];
    }
    if (lane < 16) pden[(size_t)js * N + r0w + lane] = den;
}

// ---------------- Kernel E: combine partials, div + elu ----------------
__global__ __launch_bounds__(256) void k_combine(const float* __restrict__ pacc,
                                                 const float* __restrict__ pden,
                                                 float* __restrict__ out) {
    int gid = blockIdx.x * 256 + threadIdx.x;
    int row = gid >> 6;
    float a = 0.f, d = 0.f;
    #pragma unroll
    for (int s = 0; s < JS; ++s) {
        a += pacc[((size_t)s * N + row) * 64 + (gid & 63)];
        d += pden[(size_t)s * N + row];
    }
    out[gid] = elu(a / d);
}

// ---------------- launch ----------------
extern "C" void kernel_launch(void* const* d_in, const int* in_sizes, int n_in,
                              void* d_out, int out_size, void* d_ws, size_t ws_size,
                              hipStream_t stream) {
    const float* x   = (const float*)d_in[0];
    const float* adj = (const float*)d_in[1];
    const float* W   = (const float*)d_in[2];
    const float* a   = (const float*)d_in[3];
    float* out = (float*)d_out;

    // ws layout (float units)
    float* ws    = (float*)d_ws;
    float* h     = ws;                               // 524288
    float* s1    = h + (size_t)N * FOUT;             // 8192
    float* s2    = s1 + N;                           // 8192
    unsigned* s2me = (unsigned*)(s2 + N);            // 64 slot
    float* e2p_g = (float*)s2me + 64;                // 8192
    float* e2n_g = e2p_g + N;                        // 8192
    float* pden  = e2n_g + N;                        // 16*8192
    unsigned short* hT = (unsigned short*)(pden + JS * N);   // 262144 float-equiv
    float* pacc  = (float*)hT + 262144;              // 16*524288

    hipMemsetAsync(s2me, 0, sizeof(unsigned), stream);   // fenc lower bound
    k_h<<<dim3((N * FOUT) / 256), dim3(256), 0, stream>>>(x, W, a, h, s1, s2);
    k_t<<<dim3(N / 64), dim3(256), 0, stream>>>(h, s2, hT, e2p_g, e2n_g, s2me);

    k_attn<<<dim3(128 * JS), dim3(256), 0, stream>>>(adj, hT, s1, s2me, e2p_g, e2n_g, pacc, pden);
    k_combine<<<dim3((N * FOUT) / 256), dim3(256), 0, stream>>>(pacc, pden, out);
}